// Round 4
// baseline (252.651 us; speedup 1.0000x reference)
//
#include <hip/hip_runtime.h>
#include <stdint.h>
#include <stddef.h>

#define HDN 2048
#define NH 16
#define KVH 2
#define HDIM 128
#define BB 2
#define SS 2048
#define MTOT 4096   // BB*SS
#define NQKV 2560   // 2048 + 256 + 256
#define KVB 32      // attention kv tile

typedef float f32x4 __attribute__((ext_vector_type(4)));
typedef short s16x8 __attribute__((ext_vector_type(8)));
typedef unsigned short u16;
typedef unsigned int u32;

__device__ __forceinline__ u16 f2b(float f) {
    u32 u = __builtin_bit_cast(u32, f);
    u += 0x7fffu + ((u >> 16) & 1u);
    return (u16)(u >> 16);
}
__device__ __forceinline__ float b2f(u16 u) {
    return __builtin_bit_cast(float, (u32)u << 16);
}
__device__ __forceinline__ u32 cvtpk(float lo, float hi) {
    u32 r;
    asm("v_cvt_pk_bf16_f32 %0, %1, %2" : "=v"(r) : "v"(lo), "v"(hi));
    return r;
}
__device__ __forceinline__ float fmax3(float a, float b, float c) {
    return fmaxf(fmaxf(a, b), c);
}

#define GLD_LDS16(src, dst) __builtin_amdgcn_global_load_lds( \
    (const __attribute__((address_space(1))) u32*)(src), \
    (__attribute__((address_space(3))) u32*)(dst), 16, 0, 0)

// ---------------- fp32 -> bf16 convert (8 elems/thread/iter) ----------------
__global__ void cvt_f32_bf16(const float* __restrict__ in, u16* __restrict__ out, int n8) {
    int stride = gridDim.x * blockDim.x;
    for (int idx = blockIdx.x * blockDim.x + threadIdx.x; idx < n8; idx += stride) {
        const float4* p = reinterpret_cast<const float4*>(in) + (size_t)idx * 2;
        float4 a = p[0], b = p[1];
        u16 u[8] = {f2b(a.x), f2b(a.y), f2b(a.z), f2b(a.w),
                    f2b(b.x), f2b(b.y), f2b(b.z), f2b(b.w)};
        reinterpret_cast<uint4*>(out)[idx] = *reinterpret_cast<uint4*>(u);
    }
}

// ---------------- GEMM: C[M,N] = A[M,K] * B[N,K]^T (+bias) ------------------
// 128x128 tile, BK=32, 256 threads (4 waves, 2x2), 16x16x32 bf16 MFMA.
// BIASM: 0 = none, 1 = concat bias (bq | bk | bv at col 2048 / 2304).
// CT: float or u16 (bf16) output.
template<int BIASM, typename CT>
__global__ __launch_bounds__(256) void gemm_bt(
    const u16* __restrict__ A, const u16* __restrict__ B,
    const float* __restrict__ b0, const float* __restrict__ b1,
    const float* __restrict__ b2, CT* __restrict__ C,
    int N, int K)
{
    const int tid = threadIdx.x;
    const int lane = tid & 63;
    const int w = tid >> 6;
    const int wm = w >> 1, wn = w & 1;

    // XCD-aware bijective swizzle (nwg % 8 == 0 for all our grids)
    const int gx = gridDim.x;
    int lin = blockIdx.y * gx + blockIdx.x;
    const int cpx = (gx * gridDim.y) >> 3;
    lin = (lin & 7) * cpx + (lin >> 3);
    const int bn = lin % gx;
    const int bm = lin / gx;

    __shared__ u16 As[128 * 32];
    __shared__ u16 Bs[128 * 32];

    f32x4 acc[4][4];
#pragma unroll
    for (int i = 0; i < 4; i++)
#pragma unroll
        for (int j = 0; j < 4; j++)
            acc[i][j] = (f32x4){0.f, 0.f, 0.f, 0.f};

    int srow[2], scol[2], sdst[2];
#pragma unroll
    for (int i = 0; i < 2; i++) {
        int o = w * 128 + i * 64 + lane;      // 16B slot index in [0,512)
        int r = o >> 2, s = o & 3;
        srow[i] = r;
        scol[i] = (s ^ ((r >> 1) & 3)) * 8;   // pre-swizzled source col (elems)
        sdst[i] = (w * 128 + i * 64) * 8;     // wave-uniform dest (u16 units)
    }

    const u16* Ab = A + (size_t)bm * 128 * K;
    const u16* Bb = B + (size_t)bn * 128 * K;

    int a_off[4], b_off[4];
#pragma unroll
    for (int f = 0; f < 4; f++) {
        int ra = wm * 64 + f * 16 + (lane & 15);
        a_off[f] = ra * 64 + (((lane >> 4) ^ ((ra >> 1) & 3)) << 4);
        int rb = wn * 64 + f * 16 + (lane & 15);
        b_off[f] = rb * 64 + (((lane >> 4) ^ ((rb >> 1) & 3)) << 4);
    }

    const int kiters = K >> 5;
    for (int kt = 0; kt < kiters; kt++) {
        __syncthreads();
        const int k0 = kt * 32;
#pragma unroll
        for (int i = 0; i < 2; i++) {
            GLD_LDS16(Ab + (size_t)srow[i] * K + k0 + scol[i], As + sdst[i]);
            GLD_LDS16(Bb + (size_t)srow[i] * K + k0 + scol[i], Bs + sdst[i]);
        }
        __syncthreads();
        s16x8 af[4], bfv[4];
#pragma unroll
        for (int f = 0; f < 4; f++) {
            af[f]  = *reinterpret_cast<const s16x8*>((const char*)As + a_off[f]);
            bfv[f] = *reinterpret_cast<const s16x8*>((const char*)Bs + b_off[f]);
        }
#pragma unroll
        for (int mf = 0; mf < 4; mf++)
#pragma unroll
            for (int nf = 0; nf < 4; nf++)
                acc[mf][nf] = __builtin_amdgcn_mfma_f32_16x16x32_bf16(
                    af[mf], bfv[nf], acc[mf][nf], 0, 0, 0);
    }

#pragma unroll
    for (int nf = 0; nf < 4; nf++) {
        int col = bn * 128 + wn * 64 + nf * 16 + (lane & 15);
        float bias = 0.0f;
        if (BIASM == 1)
            bias = (col < 2048) ? b0[col] : (col < 2304 ? b1[col - 2048] : b2[col - 2304]);
#pragma unroll
        for (int mf = 0; mf < 4; mf++) {
            int row0 = bm * 128 + wm * 64 + mf * 16 + ((lane >> 4) << 2);
#pragma unroll
            for (int r = 0; r < 4; r++) {
                float v = acc[mf][nf][r] + bias;
                if constexpr (__is_same(CT, u16))
                    C[(size_t)(row0 + r) * N + col] = f2b(v);
                else
                    C[(size_t)(row0 + r) * N + col] = v;
            }
        }
    }
}

// ---------------- mRoPE: bf16 in [B*S][rowstride] -> bf16 [B][nh][S][128] ---
// mul folds attention scale*log2e into Q.
__global__ void rope_kernel(const u16* __restrict__ pre, int rowstride,
                            const float* __restrict__ cosp,
                            const float* __restrict__ sinp,
                            u16* __restrict__ out, int nheads, float mul)
{
    int idx = blockIdx.x * blockDim.x + threadIdx.x; // d (64), then h, then b*s
    int total = BB * SS * nheads * 64;
    if (idx >= total) return;
    int d = idx & 63;
    int h = (idx >> 6) % nheads;
    int bs = idx / (64 * nheads);
    int b = bs / SS, s = bs % SS;
    int strm = (d < 16) ? 0 : (d < 40 ? 1 : 2);   // MROPE_SECTION [16,24,24]
    size_t cbase = ((size_t)(strm * BB + b) * SS + s) * HDIM;
    float c1 = cosp[cbase + d],      s1 = sinp[cbase + d];
    float c2 = cosp[cbase + d + 64], s2 = sinp[cbase + d + 64];
    size_t qbase = (size_t)bs * rowstride + h * HDIM;
    float q1 = b2f(pre[qbase + d]), q2 = b2f(pre[qbase + d + 64]);
    float o1 = (q1 * c1 - q2 * s1) * mul;   // rotate_half: [-x2, x1]
    float o2 = (q2 * c2 + q1 * s2) * mul;
    size_t obase = (((size_t)b * nheads + h) * SS + s) * HDIM;
    out[obase + d]      = f2b(o1);
    out[obase + d + 64] = f2b(o2);
}

// ---------------- V: bf16 strided -> bf16 V^T [B][KVH][128][S] --------------
__global__ void vt_kernel(const u16* __restrict__ src, int rowstride,
                          u16* __restrict__ Vt)
{
    __shared__ u16 tile[64][80];
    int st = blockIdx.x, dt = blockIdx.y, bk = blockIdx.z;
    int b = bk / KVH, kv = bk % KVH;
    int t = threadIdx.x;
    int r = t >> 2, c0 = (t & 3) * 16;
    const u16* p = src + (size_t)(b * SS + st * 64 + r) * rowstride
                       + kv * HDIM + dt * 64 + c0;
    *reinterpret_cast<uint4*>(&tile[r][c0])     = *reinterpret_cast<const uint4*>(p);
    *reinterpret_cast<uint4*>(&tile[r][c0 + 8]) = *reinterpret_cast<const uint4*>(p + 8);
    __syncthreads();
    u16 tmp[16];
#pragma unroll
    for (int j = 0; j < 16; j++) tmp[j] = tile[c0 + j][r];
    u16* dst = Vt + (((size_t)(b * KVH + kv) * HDIM) + dt * 64 + r) * SS + st * 64 + c0;
    *reinterpret_cast<uint4*>(dst)     = *reinterpret_cast<uint4*>(&tmp[0]);
    *reinterpret_cast<uint4*>(dst + 8) = *reinterpret_cast<uint4*>(&tmp[8]);
}

// ---------------- Flash attention, causal, GQA (swapped-operand form) -------
// grid (16, NH, B): block bx handles q-tiles {bx, 31-bx} (68 kv32-tiles, uniform).
// 4 waves x 16 q-rows. KVB=32 tiles, dbuf K/V -> 37.9KB LDS -> 4 blocks/CU.
// S^T = mfma(K,Q): lane owns q = lane&15, kv = nf*16+4g+r.
// O^T = mfma(V^T, P^T): lane owns q = lane&15, d = df*16+4g+r.
__global__ __launch_bounds__(256, 4) void attn_kernel(
    const u16* __restrict__ Qb,  // [B][NH][S][128], pre-scaled by scale*log2e
    const u16* __restrict__ Kb,  // [B][KVH][S][128]
    const u16* __restrict__ Vt,  // [B][KVH][128][S]
    u16* __restrict__ AO)        // [B][S][NH*128]
{
    const int pr = blockIdx.x, h = blockIdx.y, b = blockIdx.z;
    const int kvh = h >> 3;      // h / (NH/KVH)
    const int tid = threadIdx.x, lane = tid & 63, w = tid >> 6;
    const int g = lane >> 4, ql = lane & 15;

    __shared__ u16 Ks[2][KVB * 128];   // rows=kv (256B,16 slots), swz s^(kv&7)
    __shared__ u16 Vs[2][128 * KVB];   // rows=d  (64B, 4 slots),  swz s^((d>>2)&3)
    __shared__ u16 Ps[4][16 * 40];     // per-wave P[q][kv], row 80B (padded)

    const u16* Kbase = Kb + ((size_t)b * KVH + kvh) * SS * HDIM;
    const u16* Vbase = Vt + ((size_t)b * KVH + kvh) * HDIM * (size_t)SS;

    // staging maps: 2 K slots + 2 V slots per thread (512 slots each tile)
    int kr[2], kc[2], vd[2], vg[2], sdst[2];
#pragma unroll
    for (int i = 0; i < 2; i++) {
        int s = tid + 256 * i;
        kr[i] = s >> 4;
        kc[i] = ((s & 15) ^ (kr[i] & 7)) * 8;
        vd[i] = s >> 2;
        vg[i] = ((s & 3) ^ ((vd[i] >> 2) & 3)) * 8;
        sdst[i] = (w * 64 + 256 * i) * 8;   // wave-uniform dest (u16 units)
    }
    // lane-constant read swizzles
    const int vswz = (ql >> 2) & 3;        // vf slot XOR
    const int kswz = ql & 7;               // kf slot XOR
    const int pswz = ql & 3;               // pf 16B-slot XOR

#define STAGE(buf, kt) do {                                                    \
        const size_t kvo_ = (size_t)(kt) * KVB;                                \
        _Pragma("unroll")                                                      \
        for (int i_ = 0; i_ < 2; i_++)                                         \
            GLD_LDS16(Kbase + (kvo_ + kr[i_]) * HDIM + kc[i_],                 \
                      &Ks[buf][0] + sdst[i_]);                                 \
        _Pragma("unroll")                                                      \
        for (int i_ = 0; i_ < 2; i_++)                                         \
            GLD_LDS16(Vbase + (size_t)vd[i_] * SS + kvo_ + vg[i_],             \
                      &Vs[buf][0] + sdst[i_]);                                 \
    } while (0)

    for (int half = 0; half < 2; half++) {
        const int qt = half ? (31 - pr) : pr;
        const int qg = qt * 64 + w * 16 + ql;  // this lane's q row

        const u16* Qrow = Qb + (((size_t)b * NH + h) * SS + qg) * HDIM;
        s16x8 qf[4];
#pragma unroll
        for (int kk = 0; kk < 4; kk++)
            qf[kk] = *reinterpret_cast<const s16x8*>(Qrow + kk * 32 + g * 8);

        f32x4 oacc[8];
#pragma unroll
        for (int i = 0; i < 8; i++) oacc[i] = (f32x4){0.f, 0.f, 0.f, 0.f};
        float m_run = -1e30f, l_run = 0.0f;

        const int ntiles = 2 * qt + 2;

        STAGE(0, 0);
        asm volatile("s_waitcnt vmcnt(0) lgkmcnt(0)" ::: "memory");
        __builtin_amdgcn_s_barrier();

        for (int kt = 0; kt < ntiles; kt++) {
            const int cur = kt & 1;
            if (kt + 1 < ntiles) STAGE(cur ^ 1, kt + 1);   // prefetch under compute

            // ---- S^T tile: 32 kv x 16 q ----
            f32x4 sacc[2];
            sacc[0] = (f32x4){0.f, 0.f, 0.f, 0.f};
            sacc[1] = (f32x4){0.f, 0.f, 0.f, 0.f};
            __builtin_amdgcn_s_setprio(1);
#pragma unroll
            for (int nf = 0; nf < 2; nf++) {
                const char* Krow = (const char*)&Ks[cur][0] + (nf * 16 + ql) * 256;
#pragma unroll
                for (int kk = 0; kk < 4; kk++) {
                    s16x8 kf = *reinterpret_cast<const s16x8*>(
                        Krow + (((kk * 4 + g) ^ kswz) << 4));
                    sacc[nf] = __builtin_amdgcn_mfma_f32_16x16x32_bf16(
                        kf, qf[kk], sacc[nf], 0, 0, 0);
                }
            }
            __builtin_amdgcn_s_setprio(0);

            if (kt >= 2 * qt) {  // diagonal region: causal mask
#pragma unroll
                for (int nf = 0; nf < 2; nf++)
#pragma unroll
                    for (int r = 0; r < 4; r++) {
                        int kv = kt * KVB + nf * 16 + 4 * g + r;
                        if (kv > qg) sacc[nf][r] = -1e30f;
                    }
            }

            // ---- row max: 8 values in-lane + 2 shuffles ----
            float t0 = fmax3(sacc[0][0], sacc[0][1], sacc[0][2]);
            float t1 = fmax3(sacc[0][3], sacc[1][0], sacc[1][1]);
            float mt = fmax3(t0, t1, fmaxf(sacc[1][2], sacc[1][3]));
            mt = fmaxf(mt, __shfl_xor(mt, 16, 64));
            mt = fmaxf(mt, __shfl_xor(mt, 32, 64));

            // T13 defer-max: skip rescale while max growth <= 8 (log2 units)
            if (!__all(mt - m_run <= 8.0f)) {
                float mnew = fmaxf(m_run, mt);
                float alpha = exp2f(m_run - mnew);
                m_run = mnew;
                l_run *= alpha;
#pragma unroll
                for (int df = 0; df < 8; df++)
#pragma unroll
                    for (int r = 0; r < 4; r++) oacc[df][r] *= alpha;
            }

            float rs = 0.0f;
            uint2 pk[2];
#pragma unroll
            for (int nf = 0; nf < 2; nf++) {
                float p0 = exp2f(sacc[nf][0] - m_run);
                float p1 = exp2f(sacc[nf][1] - m_run);
                float p2 = exp2f(sacc[nf][2] - m_run);
                float p3 = exp2f(sacc[nf][3] - m_run);
                rs += (p0 + p1) + (p2 + p3);
                pk[nf].x = cvtpk(p0, p1);
                pk[nf].y = cvtpk(p2, p3);
            }
            rs += __shfl_xor(rs, 16, 64);
            rs += __shfl_xor(rs, 32, 64);
            l_run += rs;

            // P[q][kv] -> per-wave LDS (8B slots, XOR swizzle), 2x ds_write_b64
            char* Pw = (char*)&Ps[w][0];
#pragma unroll
            for (int nf = 0; nf < 2; nf++) {
                int s = nf * 4 + g;
                *reinterpret_cast<uint2*>(Pw + ql * 80 + ((s ^ (pswz << 1)) << 3)) = pk[nf];
            }

            // ---- O^T += V^T * P^T ----
            s16x8 pf = *reinterpret_cast<const s16x8*>(Pw + ql * 80 + ((g ^ pswz) << 4));
            __builtin_amdgcn_s_setprio(1);
#pragma unroll
            for (int df = 0; df < 8; df++) {
                int d = df * 16 + ql;
                s16x8 vf = *reinterpret_cast<const s16x8*>(
                    (const char*)&Vs[cur][0] + d * 64 + ((g ^ vswz) << 4));
                oacc[df] = __builtin_amdgcn_mfma_f32_16x16x32_bf16(
                    vf, pf, oacc[df], 0, 0, 0);
            }
            __builtin_amdgcn_s_setprio(0);

            // prefetch landed + everyone done reading cur (incl. LDS reads)
            asm volatile("s_waitcnt vmcnt(0) lgkmcnt(0)" ::: "memory");
            __builtin_amdgcn_s_barrier();
        }

        // epilogue: lane owns q=qg, d = df*16+4g+r -> 8B packed stores
        float invl = 1.0f / l_run;
        u16* Ao = AO + ((size_t)b * SS + qg) * HDN + h * HDIM;
#pragma unroll
        for (int df = 0; df < 8; df++) {
            uint2 val;
            val.x = cvtpk(oacc[df][0] * invl, oacc[df][1] * invl);
            val.y = cvtpk(oacc[df][2] * invl, oacc[df][3] * invl);
            *reinterpret_cast<uint2*>(Ao + df * 16 + 4 * g) = val;
        }
    }
#undef STAGE
}

// ---------------------------------------------------------------------------
extern "C" void kernel_launch(void* const* d_in, const int* in_sizes, int n_in,
                              void* d_out, int out_size, void* d_ws, size_t ws_size,
                              hipStream_t stream) {
    (void)in_sizes; (void)n_in; (void)out_size; (void)ws_size;
    const float* hs   = (const float*)d_in[0];
    const float* cosp = (const float*)d_in[1];
    const float* sinp = (const float*)d_in[2];
    // d_in[3] attention_mask: exactly causal; applied analytically
    const float* Wq = (const float*)d_in[4];
    const float* bq = (const float*)d_in[5];
    const float* Wk = (const float*)d_in[6];
    const float* bk = (const float*)d_in[7];
    const float* Wv = (const float*)d_in[8];
    const float* bv = (const float*)d_in[9];
    const float* Wo = (const float*)d_in[10];
    float* out = (float*)d_out;

    char* ws = (char*)d_ws;
    size_t off = 0;
    u16* Xb     = (u16*)(ws + off); off += (size_t)MTOT * HDN * 2;       // 16.8 MB
    u16* Wall   = (u16*)(ws + off); off += (size_t)NQKV * HDN * 2;       // 10.5 MB
    u16* Wob    = (u16*)(ws + off); off += (size_t)HDN * HDN * 2;        //  8.4 MB
    u16* QKVb   = (u16*)(ws + off); off += (size_t)MTOT * NQKV * 2;      // 21.0 MB
    u16* Qb     = (u16*)(ws + off); off += (size_t)BB * NH * SS * HDIM * 2;
    u16* Kb     = (u16*)(ws + off); off += (size_t)BB * KVH * SS * HDIM * 2;
    u16* Vtb    = (u16*)(ws + off); off += (size_t)BB * KVH * HDIM * SS * 2;
    u16* AO     = (u16*)(ws + off); off += (size_t)MTOT * HDN * 2;

    // 1) converts (Wq|Wk|Wv row-concatenated into one [2560][2048] buffer)
    cvt_f32_bf16<<<2048, 256, 0, stream>>>(hs, Xb, MTOT * HDN / 8);
    cvt_f32_bf16<<<2048, 256, 0, stream>>>(Wq, Wall, HDN * HDN / 8);
    cvt_f32_bf16<<<256,  256, 0, stream>>>(Wk, Wall + (size_t)HDN * HDN, 256 * HDN / 8);
    cvt_f32_bf16<<<256,  256, 0, stream>>>(Wv, Wall + (size_t)(HDN + 256) * HDN, 256 * HDN / 8);
    cvt_f32_bf16<<<2048, 256, 0, stream>>>(Wo, Wob, HDN * HDN / 8);

    // 2) fused QKV projection -> bf16 [4096][2560] (+concat bias)
    gemm_bt<1, u16><<<dim3(NQKV / 128, MTOT / 128), 256, 0, stream>>>(
        Xb, Wall, bq, bk, bv, QKVb, NQKV, HDN);

    // 3) mRoPE -> bf16 head-major; Q pre-scaled by 1/sqrt(D)*log2(e)
    const float qmul = 0.08838834764831845f * 1.4426950408889634f;
    rope_kernel<<<(BB * SS * NH * 64) / 256, 256, 0, stream>>>(
        QKVb, NQKV, cosp, sinp, Qb, NH, qmul);
    rope_kernel<<<(BB * SS * KVH * 64) / 256, 256, 0, stream>>>(
        QKVb + HDN, NQKV, cosp, sinp, Kb, KVH, 1.0f);

    // 4) V -> bf16 transposed [B][KVH][128][S]
    vt_kernel<<<dim3(SS / 64, HDIM / 64, BB * KVH), 256, 0, stream>>>(
        QKVb + HDN + 256, NQKV, Vtb);

    // 5) causal GQA flash attention (pair-balanced grid, 4 blocks/CU)
    attn_kernel<<<dim3(16, NH, BB), 256, 0, stream>>>(Qb, Kb, Vtb, AO);

    // 6) output projection (no bias), fp32 out
    gemm_bt<0, float><<<dim3(HDN / 128, MTOT / 128), 256, 0, stream>>>(
        AO, Wob, nullptr, nullptr, nullptr, out, HDN, HDN);
}

// Round 5
// 244.141 us; speedup vs baseline: 1.0349x; 1.0349x over previous
//
#include <hip/hip_runtime.h>
#include <stdint.h>
#include <stddef.h>

#define HDN 2048
#define NH 16
#define KVH 2
#define HDIM 128
#define BB 2
#define SS 2048
#define MTOT 4096   // BB*SS
#define NQKV 2560   // 2048 + 256 + 256
#define KVB 32      // attention kv tile

typedef float f32x4 __attribute__((ext_vector_type(4)));
typedef short s16x8 __attribute__((ext_vector_type(8)));
typedef unsigned short u16;
typedef unsigned int u32;

__device__ __forceinline__ u16 f2b(float f) {
    u32 u = __builtin_bit_cast(u32, f);
    u += 0x7fffu + ((u >> 16) & 1u);
    return (u16)(u >> 16);
}
__device__ __forceinline__ float b2f(u16 u) {
    return __builtin_bit_cast(float, (u32)u << 16);
}
__device__ __forceinline__ u32 cvtpk(float lo, float hi) {
    u32 r;
    asm("v_cvt_pk_bf16_f32 %0, %1, %2" : "=v"(r) : "v"(lo), "v"(hi));
    return r;
}
__device__ __forceinline__ float fmax3(float a, float b, float c) {
    return fmaxf(fmaxf(a, b), c);
}

#define GLD_LDS16(src, dst) __builtin_amdgcn_global_load_lds( \
    (const __attribute__((address_space(1))) u32*)(src), \
    (__attribute__((address_space(3))) u32*)(dst), 16, 0, 0)

// ---------------- fp32 -> bf16 convert (8 elems/thread/iter) ----------------
__global__ void cvt_f32_bf16(const float* __restrict__ in, u16* __restrict__ out, int n8) {
    int stride = gridDim.x * blockDim.x;
    for (int idx = blockIdx.x * blockDim.x + threadIdx.x; idx < n8; idx += stride) {
        const float4* p = reinterpret_cast<const float4*>(in) + (size_t)idx * 2;
        float4 a = p[0], b = p[1];
        u16 u[8] = {f2b(a.x), f2b(a.y), f2b(a.z), f2b(a.w),
                    f2b(b.x), f2b(b.y), f2b(b.z), f2b(b.w)};
        reinterpret_cast<uint4*>(out)[idx] = *reinterpret_cast<uint4*>(u);
    }
}

// ---------------- GEMM: C[M,N] = A[M,K] * B[N,K]^T (+bias) ------------------
// 128x128 tile, BK=32, 256 threads (4 waves, 2x2), 16x16x32 bf16 MFMA.
// BIASM: 0 = none, 1 = concat bias (bq | bk | bv at col 2048 / 2304).
// CT: float or u16 (bf16) output.
template<int BIASM, typename CT>
__global__ __launch_bounds__(256) void gemm_bt(
    const u16* __restrict__ A, const u16* __restrict__ B,
    const float* __restrict__ b0, const float* __restrict__ b1,
    const float* __restrict__ b2, CT* __restrict__ C,
    int N, int K)
{
    const int tid = threadIdx.x;
    const int lane = tid & 63;
    const int w = tid >> 6;
    const int wm = w >> 1, wn = w & 1;

    // XCD-aware bijective swizzle (nwg % 8 == 0 for all our grids)
    const int gx = gridDim.x;
    int lin = blockIdx.y * gx + blockIdx.x;
    const int cpx = (gx * gridDim.y) >> 3;
    lin = (lin & 7) * cpx + (lin >> 3);
    const int bn = lin % gx;
    const int bm = lin / gx;

    __shared__ u16 As[128 * 32];
    __shared__ u16 Bs[128 * 32];

    f32x4 acc[4][4];
#pragma unroll
    for (int i = 0; i < 4; i++)
#pragma unroll
        for (int j = 0; j < 4; j++)
            acc[i][j] = (f32x4){0.f, 0.f, 0.f, 0.f};

    int srow[2], scol[2], sdst[2];
#pragma unroll
    for (int i = 0; i < 2; i++) {
        int o = w * 128 + i * 64 + lane;      // 16B slot index in [0,512)
        int r = o >> 2, s = o & 3;
        srow[i] = r;
        scol[i] = (s ^ ((r >> 1) & 3)) * 8;   // pre-swizzled source col (elems)
        sdst[i] = (w * 128 + i * 64) * 8;     // wave-uniform dest (u16 units)
    }

    const u16* Ab = A + (size_t)bm * 128 * K;
    const u16* Bb = B + (size_t)bn * 128 * K;

    int a_off[4], b_off[4];
#pragma unroll
    for (int f = 0; f < 4; f++) {
        int ra = wm * 64 + f * 16 + (lane & 15);
        a_off[f] = ra * 64 + (((lane >> 4) ^ ((ra >> 1) & 3)) << 4);
        int rb = wn * 64 + f * 16 + (lane & 15);
        b_off[f] = rb * 64 + (((lane >> 4) ^ ((rb >> 1) & 3)) << 4);
    }

    const int kiters = K >> 5;
    for (int kt = 0; kt < kiters; kt++) {
        __syncthreads();
        const int k0 = kt * 32;
#pragma unroll
        for (int i = 0; i < 2; i++) {
            GLD_LDS16(Ab + (size_t)srow[i] * K + k0 + scol[i], As + sdst[i]);
            GLD_LDS16(Bb + (size_t)srow[i] * K + k0 + scol[i], Bs + sdst[i]);
        }
        __syncthreads();
        s16x8 af[4], bfv[4];
#pragma unroll
        for (int f = 0; f < 4; f++) {
            af[f]  = *reinterpret_cast<const s16x8*>((const char*)As + a_off[f]);
            bfv[f] = *reinterpret_cast<const s16x8*>((const char*)Bs + b_off[f]);
        }
#pragma unroll
        for (int mf = 0; mf < 4; mf++)
#pragma unroll
            for (int nf = 0; nf < 4; nf++)
                acc[mf][nf] = __builtin_amdgcn_mfma_f32_16x16x32_bf16(
                    af[mf], bfv[nf], acc[mf][nf], 0, 0, 0);
    }

#pragma unroll
    for (int nf = 0; nf < 4; nf++) {
        int col = bn * 128 + wn * 64 + nf * 16 + (lane & 15);
        float bias = 0.0f;
        if (BIASM == 1)
            bias = (col < 2048) ? b0[col] : (col < 2304 ? b1[col - 2048] : b2[col - 2304]);
#pragma unroll
        for (int mf = 0; mf < 4; mf++) {
            int row0 = bm * 128 + wm * 64 + mf * 16 + ((lane >> 4) << 2);
#pragma unroll
            for (int r = 0; r < 4; r++) {
                float v = acc[mf][nf][r] + bias;
                if constexpr (__is_same(CT, u16))
                    C[(size_t)(row0 + r) * N + col] = f2b(v);
                else
                    C[(size_t)(row0 + r) * N + col] = v;
            }
        }
    }
}

// ---------------- mRoPE: bf16 in [B*S][rowstride] -> bf16 [B][nh][S][128] ---
// mul folds attention scale*log2e into Q.
__global__ void rope_kernel(const u16* __restrict__ pre, int rowstride,
                            const float* __restrict__ cosp,
                            const float* __restrict__ sinp,
                            u16* __restrict__ out, int nheads, float mul)
{
    int idx = blockIdx.x * blockDim.x + threadIdx.x; // d (64), then h, then b*s
    int total = BB * SS * nheads * 64;
    if (idx >= total) return;
    int d = idx & 63;
    int h = (idx >> 6) % nheads;
    int bs = idx / (64 * nheads);
    int b = bs / SS, s = bs % SS;
    int strm = (d < 16) ? 0 : (d < 40 ? 1 : 2);   // MROPE_SECTION [16,24,24]
    size_t cbase = ((size_t)(strm * BB + b) * SS + s) * HDIM;
    float c1 = cosp[cbase + d],      s1 = sinp[cbase + d];
    float c2 = cosp[cbase + d + 64], s2 = sinp[cbase + d + 64];
    size_t qbase = (size_t)bs * rowstride + h * HDIM;
    float q1 = b2f(pre[qbase + d]), q2 = b2f(pre[qbase + d + 64]);
    float o1 = (q1 * c1 - q2 * s1) * mul;   // rotate_half: [-x2, x1]
    float o2 = (q2 * c2 + q1 * s2) * mul;
    size_t obase = (((size_t)b * nheads + h) * SS + s) * HDIM;
    out[obase + d]      = f2b(o1);
    out[obase + d + 64] = f2b(o2);
}

// ---------------- V: bf16 strided -> bf16 V^T [B][KVH][128][S] --------------
__global__ void vt_kernel(const u16* __restrict__ src, int rowstride,
                          u16* __restrict__ Vt)
{
    __shared__ u16 tile[64][80];
    int st = blockIdx.x, dt = blockIdx.y, bk = blockIdx.z;
    int b = bk / KVH, kv = bk % KVH;
    int t = threadIdx.x;
    int r = t >> 2, c0 = (t & 3) * 16;
    const u16* p = src + (size_t)(b * SS + st * 64 + r) * rowstride
                       + kv * HDIM + dt * 64 + c0;
    *reinterpret_cast<uint4*>(&tile[r][c0])     = *reinterpret_cast<const uint4*>(p);
    *reinterpret_cast<uint4*>(&tile[r][c0 + 8]) = *reinterpret_cast<const uint4*>(p + 8);
    __syncthreads();
    u16 tmp[16];
#pragma unroll
    for (int j = 0; j < 16; j++) tmp[j] = tile[c0 + j][r];
    u16* dst = Vt + (((size_t)(b * KVH + kv) * HDIM) + dt * 64 + r) * SS + st * 64 + c0;
    *reinterpret_cast<uint4*>(dst)     = *reinterpret_cast<uint4*>(&tmp[0]);
    *reinterpret_cast<uint4*>(dst + 8) = *reinterpret_cast<uint4*>(&tmp[8]);
}

// ---------------- Flash attention, causal, GQA (swapped-operand form) -------
// grid (32 hb, 32 m): lin = hb + 32*m. Co-resident blocks on a CU are
// lin + 256k, i.e. same hb, m in {m0, m0+8, m0+16, m0+24}. swz() maps those
// to qt = {m0, 15-m0, 16+m0, 31-m0} -> per-CU qt sum = 62 exactly (balanced),
// with 1024 blocks -> 4 blocks/CU -> 16 waves/CU.
// 4 waves x 16 q-rows, KVB=32 dbuf K/V -> 37.1KB LDS.
// S^T = mfma(K,Q): lane owns q = lane&15, kv = nf*16+4g+r.
// O^T = mfma(V^T, P^T): lane owns q = lane&15, d = df*16+4g+r.
__global__ __launch_bounds__(256, 4) void attn_kernel(
    const u16* __restrict__ Qb,  // [B][NH][S][128], pre-scaled by scale*log2e
    const u16* __restrict__ Kb,  // [B][KVH][S][128]
    const u16* __restrict__ Vt,  // [B][KVH][128][S]
    u16* __restrict__ AO)        // [B][S][NH*128]
{
    const int hb = blockIdx.x, m = blockIdx.y;
    const int h = hb & 15, b = hb >> 4;
    const int qt = (m < 8) ? m : (m < 16) ? (23 - m) : (m < 24) ? m : (55 - m);
    const int kvh = h >> 3;      // h / (NH/KVH)
    const int tid = threadIdx.x, lane = tid & 63, w = tid >> 6;
    const int g = lane >> 4, ql = lane & 15;

    __shared__ u16 Ks[2][KVB * 128];   // rows=kv (256B,16 slots), swz s^(kv&7)
    __shared__ u16 Vs[2][128 * KVB];   // 2 d-rows per 128B row; swz s^(r&7)
    __shared__ u16 Ps[4][16 * 40];     // per-wave P[q][kv], row 80B (padded)

    const u16* Kbase = Kb + ((size_t)b * KVH + kvh) * SS * HDIM;
    const u16* Vbase = Vt + ((size_t)b * KVH + kvh) * HDIM * (size_t)SS;

    // staging maps: 2 K slots + 2 V slots per thread (512 16B slots each tile)
    int kr[2], kc[2], vd[2], vc[2], sdst[2];
#pragma unroll
    for (int i = 0; i < 2; i++) {
        int s = tid + 256 * i;
        kr[i] = s >> 4;                        // K: kv row, 16 slots/row
        kc[i] = ((s & 15) ^ (kr[i] & 7)) * 8;
        int r = s >> 3, sl = s & 7;            // V: 128B rows = 2 d-rows
        int su = sl ^ (r & 7);
        vd[i] = 2 * r + (su >> 2);
        vc[i] = (su & 3) * 8;
        sdst[i] = (s) * 8;                     // linear dest (u16 units): w-uniform + lane*8
    }
    // lane-constant read swizzles
    const int kswz = ql & 7;               // K slot XOR
    const int vswz = ql >> 1;              // V slot XOR (r&7 == ql>>1)
    const int pswz = ql & 3;               // P 16B-slot XOR

#define STAGE(buf, kt) do {                                                    \
        const size_t kvo_ = (size_t)(kt) * KVB;                                \
        _Pragma("unroll")                                                      \
        for (int i_ = 0; i_ < 2; i_++)                                         \
            GLD_LDS16(Kbase + (kvo_ + kr[i_]) * HDIM + kc[i_],                 \
                      &Ks[buf][0] + sdst[i_]);                                 \
        _Pragma("unroll")                                                      \
        for (int i_ = 0; i_ < 2; i_++)                                         \
            GLD_LDS16(Vbase + (size_t)vd[i_] * SS + kvo_ + vc[i_],             \
                      &Vs[buf][0] + sdst[i_]);                                 \
    } while (0)

    const int qg = qt * 64 + w * 16 + ql;  // this lane's q row

    const u16* Qrow = Qb + (((size_t)b * NH + h) * SS + qg) * HDIM;
    s16x8 qf[4];
#pragma unroll
    for (int kk = 0; kk < 4; kk++)
        qf[kk] = *reinterpret_cast<const s16x8*>(Qrow + kk * 32 + g * 8);

    f32x4 oacc[8];
#pragma unroll
    for (int i = 0; i < 8; i++) oacc[i] = (f32x4){0.f, 0.f, 0.f, 0.f};
    float m_run = -1e30f, l_run = 0.0f;

    const int ntiles = 2 * qt + 2;

    STAGE(0, 0);
    asm volatile("s_waitcnt vmcnt(0) lgkmcnt(0)" ::: "memory");
    __builtin_amdgcn_s_barrier();

    for (int kt = 0; kt < ntiles; kt++) {
        const int cur = kt & 1;
        if (kt + 1 < ntiles) STAGE(cur ^ 1, kt + 1);   // prefetch under compute

        // ---- S^T tile: 32 kv x 16 q ----
        f32x4 sacc[2];
        sacc[0] = (f32x4){0.f, 0.f, 0.f, 0.f};
        sacc[1] = (f32x4){0.f, 0.f, 0.f, 0.f};
        __builtin_amdgcn_s_setprio(1);
#pragma unroll
        for (int nf = 0; nf < 2; nf++) {
            const char* Krow = (const char*)&Ks[cur][0] + (nf * 16 + ql) * 256;
#pragma unroll
            for (int kk = 0; kk < 4; kk++) {
                s16x8 kf = *reinterpret_cast<const s16x8*>(
                    Krow + (((kk * 4 + g) ^ kswz) << 4));
                sacc[nf] = __builtin_amdgcn_mfma_f32_16x16x32_bf16(
                    kf, qf[kk], sacc[nf], 0, 0, 0);
            }
        }
        __builtin_amdgcn_s_setprio(0);

        if (kt >= 2 * qt) {  // diagonal region: causal mask
#pragma unroll
            for (int nf = 0; nf < 2; nf++)
#pragma unroll
                for (int r = 0; r < 4; r++) {
                    int kv = kt * KVB + nf * 16 + 4 * g + r;
                    if (kv > qg) sacc[nf][r] = -1e30f;
                }
        }

        // ---- row max: 8 values in-lane + 2 shuffles ----
        float t0 = fmax3(sacc[0][0], sacc[0][1], sacc[0][2]);
        float t1 = fmax3(sacc[0][3], sacc[1][0], sacc[1][1]);
        float mt = fmax3(t0, t1, fmaxf(sacc[1][2], sacc[1][3]));
        mt = fmaxf(mt, __shfl_xor(mt, 16, 64));
        mt = fmaxf(mt, __shfl_xor(mt, 32, 64));

        // T13 defer-max: skip rescale while max growth <= 8 (log2 units)
        if (!__all(mt - m_run <= 8.0f)) {
            float mnew = fmaxf(m_run, mt);
            float alpha = exp2f(m_run - mnew);
            m_run = mnew;
            l_run *= alpha;
#pragma unroll
            for (int df = 0; df < 8; df++)
#pragma unroll
                for (int r = 0; r < 4; r++) oacc[df][r] *= alpha;
        }

        float rs = 0.0f;
        uint2 pk[2];
#pragma unroll
        for (int nf = 0; nf < 2; nf++) {
            float p0 = exp2f(sacc[nf][0] - m_run);
            float p1 = exp2f(sacc[nf][1] - m_run);
            float p2 = exp2f(sacc[nf][2] - m_run);
            float p3 = exp2f(sacc[nf][3] - m_run);
            rs += (p0 + p1) + (p2 + p3);
            pk[nf].x = cvtpk(p0, p1);
            pk[nf].y = cvtpk(p2, p3);
        }
        rs += __shfl_xor(rs, 16, 64);
        rs += __shfl_xor(rs, 32, 64);
        l_run += rs;

        // P[q][kv] -> per-wave LDS (8B slots, XOR swizzle), 2x ds_write_b64
        char* Pw = (char*)&Ps[w][0];
#pragma unroll
        for (int nf = 0; nf < 2; nf++) {
            int s = nf * 4 + g;
            *reinterpret_cast<uint2*>(Pw + ql * 80 + ((s ^ (pswz << 1)) << 3)) = pk[nf];
        }

        // ---- O^T += V^T * P^T ----
        s16x8 pf = *reinterpret_cast<const s16x8*>(Pw + ql * 80 + ((g ^ pswz) << 4));
        __builtin_amdgcn_s_setprio(1);
#pragma unroll
        for (int df = 0; df < 8; df++) {
            int r = df * 8 + (ql >> 1);        // 128B LDS row (2 d-rows packed)
            int sl = (((ql & 1) << 2) + g) ^ vswz;
            s16x8 vf = *reinterpret_cast<const s16x8*>(
                (const char*)&Vs[cur][0] + r * 128 + (sl << 4));
            oacc[df] = __builtin_amdgcn_mfma_f32_16x16x32_bf16(
                vf, pf, oacc[df], 0, 0, 0);
        }
        __builtin_amdgcn_s_setprio(0);

        // prefetch landed + everyone done reading cur (incl. LDS reads)
        asm volatile("s_waitcnt vmcnt(0) lgkmcnt(0)" ::: "memory");
        __builtin_amdgcn_s_barrier();
    }

    // epilogue: lane owns q=qg, d = df*16+4g+r -> 8B packed stores
    float invl = 1.0f / l_run;
    u16* Ao = AO + ((size_t)b * SS + qg) * HDN + h * HDIM;
#pragma unroll
    for (int df = 0; df < 8; df++) {
        uint2 val;
        val.x = cvtpk(oacc[df][0] * invl, oacc[df][1] * invl);
        val.y = cvtpk(oacc[df][2] * invl, oacc[df][3] * invl);
        *reinterpret_cast<uint2*>(Ao + df * 16 + 4 * g) = val;
    }
#undef STAGE
}

// ---------------------------------------------------------------------------
extern "C" void kernel_launch(void* const* d_in, const int* in_sizes, int n_in,
                              void* d_out, int out_size, void* d_ws, size_t ws_size,
                              hipStream_t stream) {
    (void)in_sizes; (void)n_in; (void)out_size; (void)ws_size;
    const float* hs   = (const float*)d_in[0];
    const float* cosp = (const float*)d_in[1];
    const float* sinp = (const float*)d_in[2];
    // d_in[3] attention_mask: exactly causal; applied analytically
    const float* Wq = (const float*)d_in[4];
    const float* bq = (const float*)d_in[5];
    const float* Wk = (const float*)d_in[6];
    const float* bk = (const float*)d_in[7];
    const float* Wv = (const float*)d_in[8];
    const float* bv = (const float*)d_in[9];
    const float* Wo = (const float*)d_in[10];
    float* out = (float*)d_out;

    char* ws = (char*)d_ws;
    size_t off = 0;
    u16* Xb     = (u16*)(ws + off); off += (size_t)MTOT * HDN * 2;       // 16.8 MB
    u16* Wall   = (u16*)(ws + off); off += (size_t)NQKV * HDN * 2;       // 10.5 MB
    u16* Wob    = (u16*)(ws + off); off += (size_t)HDN * HDN * 2;        //  8.4 MB
    u16* QKVb   = (u16*)(ws + off); off += (size_t)MTOT * NQKV * 2;      // 21.0 MB
    u16* Qb     = (u16*)(ws + off); off += (size_t)BB * NH * SS * HDIM * 2;
    u16* Kb     = (u16*)(ws + off); off += (size_t)BB * KVH * SS * HDIM * 2;
    u16* Vtb    = (u16*)(ws + off); off += (size_t)BB * KVH * HDIM * SS * 2;
    u16* AO     = (u16*)(ws + off); off += (size_t)MTOT * HDN * 2;

    // 1) converts (Wq|Wk|Wv row-concatenated into one [2560][2048] buffer)
    cvt_f32_bf16<<<2048, 256, 0, stream>>>(hs, Xb, MTOT * HDN / 8);
    cvt_f32_bf16<<<2048, 256, 0, stream>>>(Wq, Wall, HDN * HDN / 8);
    cvt_f32_bf16<<<256,  256, 0, stream>>>(Wk, Wall + (size_t)HDN * HDN, 256 * HDN / 8);
    cvt_f32_bf16<<<256,  256, 0, stream>>>(Wv, Wall + (size_t)(HDN + 256) * HDN, 256 * HDN / 8);
    cvt_f32_bf16<<<2048, 256, 0, stream>>>(Wo, Wob, HDN * HDN / 8);

    // 2) fused QKV projection -> bf16 [4096][2560] (+concat bias)
    gemm_bt<1, u16><<<dim3(NQKV / 128, MTOT / 128), 256, 0, stream>>>(
        Xb, Wall, bq, bk, bv, QKVb, NQKV, HDN);

    // 3) mRoPE -> bf16 head-major; Q pre-scaled by 1/sqrt(D)*log2(e)
    const float qmul = 0.08838834764831845f * 1.4426950408889634f;
    rope_kernel<<<(BB * SS * NH * 64) / 256, 256, 0, stream>>>(
        QKVb, NQKV, cosp, sinp, Qb, NH, qmul);
    rope_kernel<<<(BB * SS * KVH * 64) / 256, 256, 0, stream>>>(
        QKVb + HDN, NQKV, cosp, sinp, Kb, KVH, 1.0f);

    // 4) V -> bf16 transposed [B][KVH][128][S]
    vt_kernel<<<dim3(SS / 64, HDIM / 64, BB * KVH), 256, 0, stream>>>(
        QKVb + HDN + 256, NQKV, Vtb);

    // 5) causal GQA flash attention (balanced 1024-block grid, 4 blocks/CU)
    attn_kernel<<<dim3(32, 32), 256, 0, stream>>>(Qb, Kb, Vtb, AO);

    // 6) output projection (no bias), fp32 out
    gemm_bt<0, float><<<dim3(HDN / 128, MTOT / 128), 256, 0, stream>>>(
        AO, Wob, nullptr, nullptr, nullptr, out, HDN, HDN);
}